// Round 15
// baseline (133.251 us; speedup 1.0000x reference)
//
#include <hip/hip_runtime.h>
#include <hip/hip_fp16.h>

#define NSET 38
#define NSNAP 9
#define PART (NSNAP*NSET*64)   // 21888 elements of partial per block
#define PPB 64
#define HSTR 72                // zth row stride (fp16): 144B rows, 16B-aligned
#define PSTR 72                // ztp row stride (fp16): 144B rows, 16B-aligned
#define WHALF (8*64*64)        // fp16 weight elements

typedef unsigned int uint;
typedef __fp16 h2 __attribute__((ext_vector_type(2)));
typedef __fp16 h4 __attribute__((ext_vector_type(4)));
typedef __fp16 h8 __attribute__((ext_vector_type(8)));
typedef float  f32x4 __attribute__((ext_vector_type(4)));

#define HNEGINF 0xFC00u        // fp16 -inf bits

static __device__ __forceinline__ h2 h2max(h2 a, h2 b) {
  return __builtin_elementwise_max(a, b);
}
#define SPLIT8(v, v0, v1, v2, v3)                       \
  h2 v0 = __builtin_shufflevector(v, v, 0, 1);          \
  h2 v1 = __builtin_shufflevector(v, v, 2, 3);          \
  h2 v2 = __builtin_shufflevector(v, v, 4, 5);          \
  h2 v3 = __builtin_shufflevector(v, v, 6, 7);

// kA<CHUNKS>: 256 threads, PPB=64 points/chunk, grid 1024 -> 4 blocks/CU.
// R14 lessons applied: (1) native pk ops (asm outputs forced ~640 v_movs —
// the unexplained 2x VALU); (2) SNAPSHOT-PAIR pooling: ztpA/ztpB double
// buffer, one addend stream serves two snapshots (pool a-reads halve);
// (3) fp16 partial (pooled values are fp16 already — lossless, halves WRITE).
// zth is wave-private after s0 (wave g owns rows [16g,16g+16) as producer
// AND consumer) -> pair phase needs only 2 barriers.
// LDS 33.3 KB -> allocator occupancy target 4 blocks/CU -> VGPR cap 128 >>
// ~75 live (LDS-as-governor, proven R3/R8/R10/R11/R13/R14).
template<int CHUNKS>
__global__ __launch_bounds__(256)
void kA(const int* __restrict__ x, const float* __restrict__ w0,
        const float* __restrict__ cw, const float* __restrict__ cb,
        const float* __restrict__ pa, const __fp16* __restrict__ wf,
        __fp16* __restrict__ partialh)
{
  __shared__ __align__(16) __fp16 zth[PPB * HSTR];   // 9216 B [pt][dim] MFMA A
  __shared__ __align__(16) __fp16 ztpA[64 * PSTR];   // 9216 B [dim][pt] pool
  __shared__ __align__(16) __fp16 ztpB[64 * PSTR];   // 9216 B [dim][pt] pool
  __shared__ __align__(16) __fp16 addp[40 * 64];     // 5120 B [set][2*pr]
  __shared__ uint memb2[PPB * 2];                    //  512 B [pt][half]

  const int tid = threadIdx.x;
  const int q  = tid & 63;             // point (conv0) / dim (pool)
  const int g  = __builtin_amdgcn_readfirstlane(tid >> 6);  // wave id, uniform
  const int lr = tid & 15;             // mfma: A-row offset / B,C col (dim)
  const int lg = (tid & 63) >> 4;      // mfma: k-group / C row-group
  const int sbase = g * 10;            // set groups 10/10/10/8
  const int nset = (g == 3) ? 8 : 10;
  const __fp16 HNI = __builtin_bit_cast(__fp16, (unsigned short)0xFC00);
  const h2 H2NI = {HNI, HNI};

  // ---- helpers ----
  auto prelu_frag = [&](int sv, f32x4* C, __fp16* ztpX) {
    // frag mapping: pt = 16g + 4*lg + r, dim = 16*dt + lr  (wave-private rows)
    #pragma unroll
    for (int dt = 0; dt < 4; ++dt) {
      int dim = (dt << 4) + lr;
      float a = pa[(sv << 6) + dim];
      __fp16 zp[4];
      #pragma unroll
      for (int r = 0; r < 4; ++r) {
        float zv = C[dt][r];
        zp[r] = (__fp16)(zv > 0.f ? zv : a * zv);
        zth[((g << 4) + (lg << 2) + r) * HSTR + dim] = zp[r];
      }
      int pt0 = (g << 4) + (lg << 2);
      h4 w4 = {zp[0], zp[1], zp[2], zp[3]};
      *(h4*)&ztpX[dim * PSTR + pt0] = w4;
    }
  };
  auto mfma_layer = [&](int sv, f32x4* C) {   // z(sv+1) pre-act from zth=z(sv)
    h8 a0 = *(const h8*)&zth[((g << 4) + lr) * HSTR + (lg << 3)];
    h8 a1 = *(const h8*)&zth[((g << 4) + lr) * HSTR + 32 + (lg << 3)];
    const __fp16* wb = wf + ((size_t)sv << 12);
    #pragma unroll
    for (int dt = 0; dt < 4; ++dt) {
      float bias = cb[((sv + 1) << 6) + (dt << 4) + lr];
      f32x4 a4 = {bias, bias, bias, bias};
      h8 b0 = *(const h8*)&wb[(((dt << 4) + lr) << 6) + (lg << 3)];
      h8 b1 = *(const h8*)&wb[(((dt << 4) + lr) << 6) + 32 + (lg << 3)];
      a4 = __builtin_amdgcn_mfma_f32_16x16x32_f16(a0, b0, a4, 0, 0, 0);
      a4 = __builtin_amdgcn_mfma_f32_16x16x32_f16(a1, b1, a4, 0, 0, 0);
      C[dt] = a4;
    }
  };
  auto fold_store = [&](int sv, h2* runv, int c) {
    __fp16* pb = partialh + (size_t)blockIdx.x * PART + sv * (NSET * 64) + q;
    #pragma unroll
    for (int j = 0; j < 10; ++j) {
      if (j < nset) {                  // uniform guard (wave 3: 8 sets)
        h2 r = runv[j];
        __fp16 m = r.x > r.y ? r.x : r.y;
        int off = (sbase + j) * 64;
        if (CHUNKS == 1 || c == 0) pb[off] = m;
        else { __fp16 o = pb[off]; pb[off] = (m > o) ? m : o; }
      }
    }
  };

  #pragma unroll 1
  for (int c = 0; c < CHUNKS; ++c) {
    const int p = (blockIdx.x * CHUNKS + c) * PPB + q;

    // membership halves: waves 0,1 load 19 set-rows each (coalesced)
    if (c) __syncthreads();            // prior chunk's pool reads done
    if (tid < 128) {
      const int half = tid >> 6;
      uint m = 0;
      #pragma unroll
      for (int j = 0; j < 19; ++j)
        m |= (uint)(x[(half * 19 + j) * 65536 + p] == 1) << j;
      memb2[q * 2 + half] = m;
    }
    __syncthreads();

    // addp[j][2pr..2pr+1] halves: in-set ? 0 : -inf (built once per chunk)
    {
      uint* addp32 = (uint*)addp;
      #pragma unroll
      for (int i = tid; i < 1280; i += 256) {
        int j = i >> 5, pr = i & 31;
        uint lo0 = memb2[(2 * pr) * 2],     hi0 = memb2[(2 * pr) * 2 + 1];
        uint lo1 = memb2[(2 * pr + 1) * 2], hi1 = memb2[(2 * pr + 1) * 2 + 1];
        uint b0 = (j < 19) ? ((lo0 >> j) & 1u) : (j < 38) ? ((hi0 >> (j - 19)) & 1u) : 0u;
        uint b1 = (j < 19) ? ((lo1 >> j) & 1u) : (j < 38) ? ((hi1 >> (j - 19)) & 1u) : 0u;
        addp32[i] = (b0 ? 0u : HNEGINF) | ((b1 ? 0u : HNEGINF) << 16);
      }
    }

    // conv0: pre-act dims [16g,16g+16) of point q; weights via s_load
    float acc0[16];
    {
      float px = -1.f + (2.f / 255.f) * (float)(p & 255);
      float py = -1.f + (2.f / 255.f) * (float)(p >> 8);
      #pragma unroll
      for (int d = 0; d < 16; ++d) {
        int dd = (g << 4) + d;
        acc0[d] = fmaf(px, w0[2 * dd], fmaf(py, w0[2 * dd + 1], cb[dd]));
      }
    }
    __syncthreads();                   // addp ready

    // ---- s = 0 (conv0 layout: thread=pt, 16 dims; cross-wave zth) ----
    #pragma unroll
    for (int d = 0; d < 16; ++d) {
      int dd = (g << 4) + d;
      float zv = acc0[d];
      float a = pa[dd];
      __fp16 zp = (__fp16)(zv > 0.f ? zv : a * zv);
      zth[q * HSTR + dd] = zp;
      ztpA[dd * PSTR + q] = zp;
    }
    __syncthreads();                   // zth(0)/ztpA ready (cross-wave)

    f32x4 Cf[4], Cf2[4];
    mfma_layer(0, Cf);                 // Cf = pre-act z(1); VMEM hides in pool

    {                                  // pool s=0 (single buffer)
      h2 runA[10];
      #pragma unroll
      for (int j = 0; j < 10; ++j) runA[j] = H2NI;
      #pragma unroll 2
      for (int c4 = 0; c4 < 8; ++c4) {
        h8 va = *(const h8*)&ztpA[q * PSTR + (c4 << 3)];
        SPLIT8(va, va0, va1, va2, va3)
        #pragma unroll
        for (int j = 0; j < 10; ++j) {
          h8 a8 = *(const h8*)&addp[((sbase + j) << 6) + (c4 << 3)];
          SPLIT8(a8, a0, a1, a2, a3)
          runA[j] = h2max(runA[j],
                     h2max(h2max(va0 + a0, va1 + a1), h2max(va2 + a2, va3 + a3)));
        }
      }
      fold_store(0, runA, c);
    }

    // ---- pairs (1,2),(3,4),(5,6),(7,8) ----
    #pragma unroll 1
    for (int sp = 0; sp < 4; ++sp) {
      const int s = 1 + 2 * sp;
      __syncthreads();                 // prior pool reads of ztpA/B done
      prelu_frag(s, Cf, ztpA);         // zth=z(s) (wave-private rows)
      mfma_layer(s, Cf2);              // Cf2 = pre-act z(s+1)
      prelu_frag(s + 1, Cf2, ztpB);    // zth=z(s+1)
      if (sp < 3) mfma_layer(s + 1, Cf);  // Cf = pre-act z(s+2)
      __syncthreads();                 // ztpA/ztpB visible

      h2 runA[10], runB[10];
      #pragma unroll
      for (int j = 0; j < 10; ++j) { runA[j] = H2NI; runB[j] = H2NI; }
      #pragma unroll 2
      for (int c4 = 0; c4 < 8; ++c4) {
        h8 va = *(const h8*)&ztpA[q * PSTR + (c4 << 3)];
        h8 vb = *(const h8*)&ztpB[q * PSTR + (c4 << 3)];
        SPLIT8(va, va0, va1, va2, va3)
        SPLIT8(vb, vb0, vb1, vb2, vb3)
        #pragma unroll
        for (int j = 0; j < 10; ++j) {
          h8 a8 = *(const h8*)&addp[((sbase + j) << 6) + (c4 << 3)];
          SPLIT8(a8, a0, a1, a2, a3)
          runA[j] = h2max(runA[j],
                     h2max(h2max(va0 + a0, va1 + a1), h2max(va2 + a2, va3 + a3)));
          runB[j] = h2max(runB[j],
                     h2max(h2max(vb0 + a0, vb1 + a1), h2max(vb2 + a2, vb3 + a3)));
        }
      }
      fold_store(s, runA, c);
      fold_store(s + 1, runB, c);
    }
  }
}

// one-shot: cw f32 -> fp16 (RNE) into workspace
__global__ __launch_bounds__(256) void kW(const float* __restrict__ cw,
                                          __fp16* __restrict__ wf)
{
  int i = blockIdx.x * 256 + threadIdx.x;
  if (i < WHALF) wf[i] = (__fp16)cw[i];
}

// stage-1 reduce: y-slice reduces nblk/32 fp16 block-partials -> f32 buf32
__global__ __launch_bounds__(256) void kB1(const __fp16* __restrict__ ph,
    float* __restrict__ buf32, int per)
{
  int idx = blockIdx.x * 256 + threadIdx.x;
  if (idx >= PART) return;
  const __fp16* p0 = ph + (size_t)blockIdx.y * per * PART + idx;
  float mx = -3e38f;
  #pragma unroll 8
  for (int b = 0; b < per; ++b)
    mx = fmaxf(mx, (float)p0[(size_t)b * PART]);
  buf32[(size_t)blockIdx.y * PART + idx] = mx;
}

// stage-2: reduce 32 slices + zero-point chain (folded kZ, f32 exact) + feat
__global__ __launch_bounds__(256) void kB2(const float* __restrict__ buf32,
    const float* __restrict__ cw, const float* __restrict__ cb,
    const float* __restrict__ pa, float* __restrict__ feat)
{
  __shared__ float zl[64];
  __shared__ float zc[NSNAP][64];
  __shared__ float zp[NSNAP][64];
  int tid = threadIdx.x;
  int d = tid & 63;
  float z = cb[d];
  #pragma unroll 1
  for (int s = 0; s < NSNAP; ++s) {
    if (tid < 64) {
      zc[s][d] = z;
      float a = pa[(s << 6) + d];
      float v = z > 0.f ? z : a * z;
      zp[s][d] = v;
      zl[d] = v;
    }
    __syncthreads();
    if (s < 8) {
      if (tid < 64) {
        float a2 = cb[((s + 1) << 6) + d];
        for (int k = 0; k < 64; ++k)
          a2 = fmaf(zl[k], cw[(s << 12) + (d << 6) + k], a2);
        z = a2;
      }
    }
    __syncthreads();
  }

  int idx = blockIdx.x * 256 + tid;
  if (idx >= PART) return;
  int s = idx / (NSET * 64);
  int r = idx - s * (NSET * 64);
  int set = r >> 6;
  int dd = r & 63;
  float mx = -3e38f;
  #pragma unroll
  for (int y = 0; y < 32; ++y)
    mx = fmaxf(mx, buf32[(size_t)y * PART + idx]);
  int b = set / 19, cc = set - b * 19;
  float even_v, odd_v;
  if (mx < -5e37f) {                 // empty set -> zero-point snapshot
    even_v = zc[s][dd];
    odd_v  = zp[s][dd];
  } else {
    odd_v = mx;                      // prelu-domain max
    float a = pa[(s << 6) + dd];
    even_v = mx > 0.f ? mx : mx / a; // inverse prelu
  }
  size_t fb = ((size_t)b * 18 + 2 * s) * 1216 + cc * 64 + dd;
  feat[fb] = even_v;
  feat[fb + 1216] = odd_v;
}

// out[b][17-lr][srow] = scale*<feat[b][lr], fcw[lr][srow]> + fcb[lr][srow]
__global__ __launch_bounds__(256) void kC(const float* __restrict__ feat,
    const float* __restrict__ fcw, const float* __restrict__ fcb,
    float* __restrict__ out)
{
  __shared__ float f0[1216], f1[1216];
  int lr = blockIdx.y;
  int chunk = blockIdx.x;       // 0..31, 16 rows each
  int tid = threadIdx.x;
  for (int i = tid; i < 1216; i += 256) {
    f0[i] = feat[(size_t)(0 * 18 + lr) * 1216 + i];
    f1[i] = feat[(size_t)(1 * 18 + lr) * 1216 + i];
  }
  __syncthreads();
  int wv = tid >> 6, lane = tid & 63;
  float scale = 1.f / sqrtf(1216.f);
  int l = 17 - lr;
  #pragma unroll 1
  for (int rr = 0; rr < 4; ++rr) {
    int srow = (chunk << 4) + (wv << 2) + rr;
    const float* wrow = fcw + ((size_t)lr * 512 + srow) * 1216;
    float pp0 = 0.f, pp1 = 0.f;
    #pragma unroll
    for (int k = 0; k < 19; ++k) {
      float w = wrow[(k << 6) + lane];
      pp0 = fmaf(w, f0[(k << 6) + lane], pp0);
      pp1 = fmaf(w, f1[(k << 6) + lane], pp1);
    }
    #pragma unroll
    for (int off = 32; off; off >>= 1) {
      pp0 += __shfl_xor(pp0, off, 64);
      pp1 += __shfl_xor(pp1, off, 64);
    }
    if (lane == 0) {
      float b = fcb[lr * 512 + srow];
      out[((size_t)0 * 18 + l) * 512 + srow] = fmaf(scale, pp0, b);
      out[((size_t)1 * 18 + l) * 512 + srow] = fmaf(scale, pp1, b);
    }
  }
}

extern "C" void kernel_launch(void* const* d_in, const int* in_sizes, int n_in,
                              void* d_out, int out_size, void* d_ws, size_t ws_size,
                              hipStream_t stream) {
  const int*   x   = (const int*)d_in[0];
  const float* w0  = (const float*)d_in[1];
  const float* cw  = (const float*)d_in[2];
  const float* cb  = (const float*)d_in[3];
  const float* pa  = (const float*)d_in[4];
  const float* fcw = (const float*)d_in[5];
  const float* fcb = (const float*)d_in[6];
  float* out = (float*)d_out;
  char* base = (char*)d_ws;

  // ws: fp16 partial | f32 buf32[32*PART] | f32 feat | fp16 wf
  #define NEED(n) ((size_t)(n) * PART * 2 + (size_t)32 * PART * 4 \
                   + (size_t)2 * 18 * 1216 * 4 + (size_t)WHALF * 2)

  int nblk;
  if      (ws_size >= NEED(1024)) nblk = 1024;
  else if (ws_size >= NEED(512))  nblk = 512;
  else                            nblk = 256;

  __fp16* partialh = (__fp16*)base;
  float*  buf32 = (float*)(base + (size_t)nblk * PART * 2);
  float*  feat  = buf32 + (size_t)32 * PART;
  __fp16* wf    = (__fp16*)(feat + (size_t)2 * 18 * 1216);
  const int per = nblk >> 5;    // blocks per kB1 y-slice (32 slices)

  hipLaunchKernelGGL(kW, dim3(WHALF / 256), dim3(256), 0, stream, cw, wf);

  if (nblk == 1024) {
    hipLaunchKernelGGL(kA<1>, dim3(1024), dim3(256), 0, stream,
                       x, w0, cw, cb, pa, wf, partialh);
  } else if (nblk == 512) {
    hipLaunchKernelGGL(kA<2>, dim3(512), dim3(256), 0, stream,
                       x, w0, cw, cb, pa, wf, partialh);
  } else {
    hipLaunchKernelGGL(kA<4>, dim3(256), dim3(256), 0, stream,
                       x, w0, cw, cb, pa, wf, partialh);
  }

  hipLaunchKernelGGL(kB1, dim3(86, 32), dim3(256), 0, stream,
                     partialh, buf32, per);
  hipLaunchKernelGGL(kB2, dim3(86), dim3(256), 0, stream,
                     buf32, cw, cb, pa, feat);
  hipLaunchKernelGGL(kC, dim3(32, 18), dim3(256), 0, stream, feat, fcw, fcb, out);
}